// Round 24
// baseline (72.715 us; speedup 1.0000x reference)
//
#include <hip/hip_runtime.h>
#include <hip/hip_bf16.h>
#include <math.h>

#define BATCH  2
#define SEQ    2048
#define DMODEL 256
#define DSTATE 16
#define DINNER 512
#define RTOT   4096
#define GCH    128
#define LCH    16
#define NW1    (2*DINNER*DMODEL)   // 262144
#define NW2    (DMODEL*DINNER)     // 131072
#define NXPW   (48*512)            // 24576
#define NDTW   (512*16)            // 8192

typedef float f32x4 __attribute__((ext_vector_type(4)));
typedef short s16x8 __attribute__((ext_vector_type(8)));

__device__ __forceinline__ float silu_f(float v){ return v / (1.f + __expf(-v)); }
__device__ __forceinline__ ushort f2bf(float f){
  __hip_bfloat16 h = __float2bfloat16(f);
  return *reinterpret_cast<ushort*>(&h);
}
__device__ __forceinline__ float bf2f(ushort u){
  union { unsigned int i; float f; } c; c.i = ((unsigned int)u) << 16; return c.f;
}

// ---- workspace layout (float offsets; S/H bf16 in fp32-sized slots) ----
#define OFF_BC   0
#define OFF_S    (OFF_BC + RTOT*32)          // Sbuf (bf16) [chunk][n][d]
#define OFF_H    (OFF_S + 2*GCH*16*512)      // Hinit (bf16) [chunk][d][n]  (transposed for scan2 reads)
#define OFF_ANV  (OFF_H + 2*GCH*16*512)      // 16*512 fp32
#define OFF_SD   (OFF_ANV + 16*512)          // sumd fp32
#define OFF_US   (OFF_SD + 2*GCH*512)
#define UOFF_WOB ((size_t)0)
#define UOFF_XZ  (UOFF_WOB + (size_t)NW2)
#define UOFF_XC  (UOFF_XZ + (size_t)RTOT*1024)
#define UOFF_DL  (UOFF_XC + (size_t)RTOT*512)
#define UOFF_YG  (UOFF_DL + (size_t)RTOT*512)
#define UOFF_XPW (UOFF_YG + (size_t)RTOT*512)
#define UOFF_DTW (UOFF_XPW + (size_t)NXPW)

// ======== kernel 1: RMSNorm-into-LDS + B-panel cvt + GEMM1 (128x128) + cvt tails ========
__global__ __launch_bounds__(256) void k_g1(const float* __restrict__ x,
                                            const float* __restrict__ norm_w,
                                            const float* __restrict__ w_in,
                                            const float* __restrict__ w_out,
                                            const float* __restrict__ xpw,
                                            const float* __restrict__ dtw,
                                            const float* __restrict__ A_log,
                                            ushort* __restrict__ wob,
                                            ushort* __restrict__ xpwb,
                                            ushort* __restrict__ dtwb,
                                            float* __restrict__ anv,
                                            ushort* __restrict__ xzb){
  __shared__ ushort As[128][264];
  __shared__ ushort Bls[128][264];
  __shared__ float red[4][64];
  int bid = blockIdx.x;
  int t = threadIdx.x;
  // tails: out_proj cvt + xpw/dtw cvt + A-table
  {
    if (t < 128) {
      int base = bid * 512 + t * 4;
      float4 v = *reinterpret_cast<const float4*>(&w_out[base]);
      ushort4 o; o.x = f2bf(v.x); o.y = f2bf(v.y); o.z = f2bf(v.z); o.w = f2bf(v.w);
      *reinterpret_cast<ushort4*>(&wob[base]) = o;
    } else if (t < 160) {
      int base = (bid * 32 + (t - 128)) * 4;     // [0, 32768)
      if (base < NXPW) {
        float4 v = *reinterpret_cast<const float4*>(&xpw[base]);
        ushort4 o; o.x = f2bf(v.x); o.y = f2bf(v.y); o.z = f2bf(v.z); o.w = f2bf(v.w);
        *reinterpret_cast<ushort4*>(&xpwb[base]) = o;
      } else {
        int j = base - NXPW;
        float4 v = *reinterpret_cast<const float4*>(&dtw[j]);
        ushort4 o; o.x = f2bf(v.x); o.y = f2bf(v.y); o.z = f2bf(v.z); o.w = f2bf(v.w);
        *reinterpret_cast<ushort4*>(&dtwb[j]) = o;
      }
    }
    if (bid < 32) {
      int e = bid * 256 + t;           // e = n*512 + d
      int n = e >> 9, d = e & 511;
      anv[e] = -__expf(A_log[d * 16 + n]);
    }
  }
  int mB = bid >> 3, nB = bid & 7;
  int m0 = mB * 128, n0 = nB * 128;
  int b = mB >> 4;
  int l0 = (mB & 15) << 7;
  const float* xb = x + (size_t)b * DMODEL * SEQ;
  int ll = t & 63, cq = t >> 6;
  // ---- RMSNorm into As (two 64-row halves) ----
  for (int half = 0; half < 2; ++half) {
    int l = l0 + half * 64 + ll;
    float ss = 0.f;
    for (int it = 0; it < 64; ++it) {
      int c = cq * 64 + it;
      float v = xb[(size_t)c * SEQ + l];
      ss += v * v;
    }
    red[cq][ll] = ss;
    __syncthreads();
    float s = red[0][ll] + red[1][ll] + red[2][ll] + red[3][ll];
    float r = rsqrtf(s * (1.f / DMODEL) + 1e-5f);
    for (int it = 0; it < 64; ++it) {
      int c = cq * 64 + it;
      float v = xb[(size_t)c * SEQ + l];
      As[half * 64 + ll][c] = f2bf(v * r * norm_w[c]);
    }
    __syncthreads();
  }
  // ---- B-panel cvt into Bls ----
  {
    int r = t >> 1, ch = t & 1;
    const float* wr_ = &w_in[(size_t)(n0 + r) * DMODEL + ch * 128];
#pragma unroll
    for (int j = 0; j < 32; ++j) {
      float4 v = *reinterpret_cast<const float4*>(&wr_[j * 4]);
      ushort4 o; o.x = f2bf(v.x); o.y = f2bf(v.y); o.z = f2bf(v.z); o.w = f2bf(v.w);
      *reinterpret_cast<ushort4*>(&Bls[r][ch * 128 + j * 4]) = o;
    }
  }
  __syncthreads();
  // ---- GEMM from LDS (K=256) ----
  int w = t >> 6, l = t & 63;
  int wr = w >> 1, wc = w & 1;
  f32x4 acc[4][4] = {};
#pragma unroll
  for (int ks = 0; ks < 8; ++ks) {
    int kk = ks * 32 + 8 * (l >> 4);
    s16x8 af[4], bf[4];
#pragma unroll
    for (int i = 0; i < 4; ++i) {
      af[i] = *reinterpret_cast<const s16x8*>(&As[wr * 64 + i * 16 + (l & 15)][kk]);
      bf[i] = *reinterpret_cast<const s16x8*>(&Bls[wc * 64 + i * 16 + (l & 15)][kk]);
    }
#pragma unroll
    for (int mi = 0; mi < 4; ++mi)
#pragma unroll
      for (int ni = 0; ni < 4; ++ni)
        acc[mi][ni] = __builtin_amdgcn_mfma_f32_16x16x32_bf16(af[mi], bf[ni], acc[mi][ni], 0, 0, 0);
  }
  int rq = l >> 4, cc = l & 15;
#pragma unroll
  for (int mi = 0; mi < 4; ++mi)
#pragma unroll
    for (int ni = 0; ni < 4; ++ni) {
      int n = n0 + wc * 64 + ni * 16 + cc;
      int mB2 = m0 + wr * 64 + mi * 16 + rq * 4;
#pragma unroll
      for (int r2 = 0; r2 < 4; ++r2)
        xzb[(size_t)(mB2 + r2) * 1024 + n] = f2bf(acc[mi][ni][r2]);
    }
}

// ======== kernel 2: FUSED conv + x_proj + dt_proj + scan1 (256 blocks x 512 threads) ========
__global__ __launch_bounds__(512, 4) void k_xps1(const ushort* __restrict__ xzb,
                                                 const float* __restrict__ conv_w,
                                                 const float* __restrict__ conv_b,
                                                 const ushort* __restrict__ xpwb,  // [48][512]
                                                 const ushort* __restrict__ dtwb,  // [512][16]
                                                 const float* __restrict__ dtb,
                                                 const float* __restrict__ anv,
                                                 ushort* __restrict__ xcb,
                                                 float* __restrict__ BCbuf,
                                                 ushort* __restrict__ delt,
                                                 ushort* __restrict__ Sbuf,
                                                 float* __restrict__ sumd){
  __shared__ ushort xcs[16][520];      // conv+silu output (bf16), all 512 d
  __shared__ float red[8][3][256];     // x_proj per-wave partials (8 waves)
  __shared__ ushort dts_s[16][40];     // dt pre-acts (K-pad to 32 with zeros)
  __shared__ float bcs[16][32];        // B,C per row
  __shared__ ushort dl_s[16][520];     // delta, all 512 d
  int chunk = blockIdx.x;              // [0,256)
  int b = chunk >> 7;
  int base = chunk * 16;               // == b*SEQ + g*16
  int l0 = (chunk & 127) * 16;
  int t = threadIdx.x;                 // [0,512)
  int w = t >> 6, l = t & 63;
  int rq = l >> 4, cc = l & 15;
  // zero ALL 384 pad slots (rows 0..15, cols 16..39)
  if (t < 384) dts_s[t / 24][16 + t % 24] = 0;
  // ---- conv + SiLU: thread owns d = t (single column) ----
  {
    int d0 = t;
    ushort xv[19];
#pragma unroll
    for (int rr = 0; rr < 19; ++rr) {
      ushort v = 0;
      int ls = l0 - 3 + rr;
      if (ls >= 0)
        v = xzb[((size_t)(b * SEQ + ls)) * 1024 + d0];
      xv[rr] = v;
    }
    float4 cw = *reinterpret_cast<const float4*>(&conv_w[d0 * 4]);
    float bb = conv_b[d0];
#pragma unroll
    for (int r = 0; r < 16; ++r) {
      float a = bb;
      a += bf2f(xv[r + 0]) * cw.x;
      a += bf2f(xv[r + 1]) * cw.y;
      a += bf2f(xv[r + 2]) * cw.z;
      a += bf2f(xv[r + 3]) * cw.w;
      ushort o = f2bf(silu_f(a));
      xcs[r][d0] = o;
      xcb[((size_t)(base + r)) * 512 + d0] = o;
    }
  }
  __syncthreads();
  // ---- x_proj: M=16 N=48 K=512, K-split across 8 waves (64 each) ----
  {
    f32x4 acc[3] = {};
#pragma unroll
    for (int ks = 0; ks < 2; ++ks) {
      int kk = w * 64 + ks * 32 + 8 * rq;
      s16x8 af = *reinterpret_cast<const s16x8*>(&xcs[cc][kk]);
#pragma unroll
      for (int ni = 0; ni < 3; ++ni) {
        s16x8 bf = *reinterpret_cast<const s16x8*>(&xpwb[(size_t)(ni * 16 + cc) * 512 + kk]);
        acc[ni] = __builtin_amdgcn_mfma_f32_16x16x32_bf16(af, bf, acc[ni], 0, 0, 0);
      }
    }
#pragma unroll
    for (int ni = 0; ni < 3; ++ni)
      *reinterpret_cast<f32x4*>(&red[w][ni][l * 4]) = acc[ni];
  }
  __syncthreads();
  // ---- reduce 8 K-partials -> dts_s (bf16), bcs LDS, BCbuf global ----
  if (t < 192) {
    int ni = t >> 6, lr = t & 63;
    f32x4 s = *reinterpret_cast<const f32x4*>(&red[0][ni][lr * 4]);
#pragma unroll
    for (int ww = 1; ww < 8; ++ww)
      s += *reinterpret_cast<const f32x4*>(&red[ww][ni][lr * 4]);
    int rr = lr >> 4, nc = lr & 15;
#pragma unroll
    for (int r2 = 0; r2 < 4; ++r2) {
      int row = rr * 4 + r2;
      if (ni == 0) dts_s[row][nc] = f2bf(s[r2]);
      else {
        bcs[row][(ni - 1) * 16 + nc] = s[r2];
        BCbuf[(size_t)(base + row) * 32 + (ni - 1) * 16 + nc] = s[r2];
      }
    }
  }
  __syncthreads();
  // ---- dt_proj: M=16, N=512 (64 per wave), K=32 (16 real) + softplus ----
  {
    int kk2 = 8 * rq;
    s16x8 af2 = *reinterpret_cast<const s16x8*>(&dts_s[cc][kk2]);
    f32x4 acc2[4] = {};
#pragma unroll
    for (int ni = 0; ni < 4; ++ni) {
      s16x8 bf2 = {0, 0, 0, 0, 0, 0, 0, 0};
      if (kk2 < 16) {
        int dglob = w * 64 + ni * 16 + cc;
        bf2 = *reinterpret_cast<const s16x8*>(&dtwb[dglob * 16 + kk2]);
      }
      acc2[ni] = __builtin_amdgcn_mfma_f32_16x16x32_bf16(af2, bf2, acc2[ni], 0, 0, 0);
    }
#pragma unroll
    for (int ni = 0; ni < 4; ++ni) {
      int dglob = w * 64 + ni * 16 + cc;
      float bias = dtb[dglob];
#pragma unroll
      for (int r2 = 0; r2 < 4; ++r2) {
        int row = rq * 4 + r2;
        float s = acc2[ni][r2] + bias;
        float sp = (s > 15.f) ? s : log1pf(__expf(s));
        ushort u = f2bf(sp);
        dl_s[row][dglob] = u;
        delt[(size_t)(base + row) * 512 + dglob] = u;
      }
    }
  }
  __syncthreads();
  // ---- scan pass 1 from LDS -> Sbuf (bf16), sumd; thread owns d = t ----
  {
    int d = t;
    float an[16], h[16];
#pragma unroll
    for (int n = 0; n < 16; ++n) { an[n] = anv[n * 512 + d]; h[n] = 0.f; }
    float sd = 0.f;
    for (int s = 0; s < LCH; ++s) {
      float dl = bf2f(dl_s[s][d]);
      float xv = bf2f(xcs[s][d]);
      float dx = dl * xv;
      sd += dl;
#pragma unroll
      for (int n = 0; n < 16; ++n) {
        float dA = __expf(dl * an[n]);
        h[n] = dA * h[n] + dx * bcs[s][n];
      }
    }
    sumd[(size_t)chunk * 512 + d] = sd;
#pragma unroll
    for (int n = 0; n < 16; ++n)
      Sbuf[((size_t)chunk * 16 + n) * 512 + d] = f2bf(h[n]);
  }
}

// ======== kernel 3: chunk combine -> Hinit bf16 [chunk][d][n] (1024 blocks) ========
__global__ __launch_bounds__(256) void k_comb(const float* __restrict__ sumd,
                                              const ushort* __restrict__ Sbuf,
                                              const float* __restrict__ anv,
                                              ushort* __restrict__ Hinit){
  __shared__ float PL[16 * 16];
  __shared__ float SL[16 * 16];
  int bid = blockIdx.x;            // 1024 = b(1) n(4) d0(5)
  int b = bid >> 9, n = (bid >> 5) & 15, d0 = (bid & 31) * 16;
  int t = threadIdx.x;
  int j = t >> 4, dl = t & 15;     // 16 segments x 16 d
  int d = d0 + dl;
  float an = anv[n * 512 + d];
  float Pa[8], Sa[8];
  float P = 1.f, S = 0.f;
#pragma unroll
  for (int i = 0; i < 8; ++i) {
    int c = b * GCH + j * 8 + i;
    float sd = sumd[(size_t)c * 512 + d];
    float p = __expf(an * sd);
    float s = bf2f(Sbuf[((size_t)c * 16 + n) * 512 + d]);
    Pa[i] = p; Sa[i] = s;
    S = p * S + s; P *= p;
  }
  PL[j * 16 + dl] = P; SL[j * 16 + dl] = S;
  __syncthreads();
  if (t < 16) {
    float hp = 0.f;
    for (int jj = 0; jj < 16; ++jj) {
      float p = PL[jj * 16 + t], s = SL[jj * 16 + t];
      SL[jj * 16 + t] = hp;
      hp = p * hp + s;
    }
  }
  __syncthreads();
  float h = SL[j * 16 + dl];
#pragma unroll
  for (int i = 0; i < 8; ++i) {
    int c = b * GCH + j * 8 + i;
    Hinit[((size_t)c * 512 + d) * 16 + n] = f2bf(h);   // transposed: n contiguous
    h = Pa[i] * h + Sa[i];
  }
}

// ======== kernel 4: scan pass 2 with LDS-staged tiles (512 blocks, 4 blocks/CU) ========
__global__ __launch_bounds__(256, 4) void k_scan2(const ushort* __restrict__ deltab,
                                                  const ushort* __restrict__ xcb,
                                                  const ushort* __restrict__ xzb,
                                                  const float* __restrict__ BCbuf,
                                                  const float* __restrict__ anv,
                                                  const ushort* __restrict__ Hinit,
                                                  const float* __restrict__ Dw,
                                                  ushort* __restrict__ ygb){
  __shared__ ushort dl_s[16][260];
  __shared__ ushort xc_s[16][260];
  __shared__ ushort z_s [16][260];
  __shared__ float bcs[LCH][32];
  int bid = blockIdx.x;
  int b = bid >> 8;
  int g = (bid >> 1) & 127;
  int dh = bid & 1;
  int t = threadIdx.x;
  int d = dh * 256 + t;
  int base = b * SEQ + g * LCH;
  // ---- coalesced staging: 3 tiles x 512 int4-slots, 6 loads/thread ----
#pragma unroll
  for (int i = 0; i < 6; ++i) {
    int slot = i * 256 + t;            // [0,1536)
    int tile = slot >> 9;              // 0:delta 1:xc 2:z
    int idx = slot & 511;
    int row = idx >> 5, c16 = idx & 31;
    int col = dh * 256 + c16 * 8;
    size_t grow = (size_t)(base + row);
    int4 v;
    if (tile == 0)      v = *reinterpret_cast<const int4*>(&deltab[grow * 512 + col]);
    else if (tile == 1) v = *reinterpret_cast<const int4*>(&xcb[grow * 512 + col]);
    else                v = *reinterpret_cast<const int4*>(&xzb[grow * 1024 + 512 + col]);
    ushort (*dst)[260] = (tile == 0) ? dl_s : (tile == 1) ? xc_s : z_s;
    *reinterpret_cast<int4*>(&dst[row][c16 * 8]) = v;
  }
  {
    float2 v = *reinterpret_cast<const float2*>(&BCbuf[(size_t)base * 32 + t * 2]);
    *reinterpret_cast<float2*>(&((float*)bcs)[t * 2]) = v;
  }
  __syncthreads();
  float an[16], h[16];
  // Hinit transposed [chunk][d][n]: 16 contiguous bf16 = 2 int4 loads, coalesced
  {
    size_t hb0 = ((size_t)(b * GCH + g) * 512 + d) * 16;
    ushort hv[16];
    *reinterpret_cast<int4*>(&hv[0]) = *reinterpret_cast<const int4*>(&Hinit[hb0]);
    *reinterpret_cast<int4*>(&hv[8]) = *reinterpret_cast<const int4*>(&Hinit[hb0 + 8]);
#pragma unroll
    for (int n = 0; n < 16; ++n) { an[n] = anv[n * 512 + d]; h[n] = bf2f(hv[n]); }
  }
  float Dd = Dw[d];
  for (int s = 0; s < LCH; ++s) {
    float dl = bf2f(dl_s[s][t]);
    float xv = bf2f(xc_s[s][t]);
    float dx = dl * xv;
    float y = 0.f;
#pragma unroll
    for (int n = 0; n < 16; ++n) {
      float dA = __expf(dl * an[n]);
      h[n] = dA * h[n] + dx * bcs[s][n];
      y += h[n] * bcs[s][16 + n];
    }
    float zg = silu_f(bf2f(z_s[s][t]));
    ygb[(size_t)(base + s) * 512 + d] = f2bf((y + xv * Dd) * zg);
  }
}

// ======== kernel 5: GEMM3 64x64 tiles (256 blocks) out = residual + yg.Wout^T ========
__global__ __launch_bounds__(256) void k_gemm3(const ushort* __restrict__ A,
                                               const ushort* __restrict__ B,
                                               const float* __restrict__ x,
                                               float* __restrict__ out){
  __shared__ ushort Als[64][72];
  __shared__ ushort Bls[64][72];
  int m0 = blockIdx.x * 64, n0 = blockIdx.y * 64;
  int t = threadIdx.x;
  int w = t >> 6, l = t & 63;
  int wr = w >> 1, wc = w & 1;
  f32x4 acc[2][2] = {};
  int sr = t >> 3, sc = t & 7;
  for (int k0 = 0; k0 < DINNER; k0 += 64) {
#pragma unroll
    for (int p = 0; p < 2; ++p) {
      int r = sr + p * 32;
      *reinterpret_cast<int4*>(&Als[r][sc * 8]) =
        *reinterpret_cast<const int4*>(&A[((size_t)(m0 + r)) * DINNER + k0 + sc * 8]);
      *reinterpret_cast<int4*>(&Bls[r][sc * 8]) =
        *reinterpret_cast<const int4*>(&B[((size_t)(n0 + r)) * DINNER + k0 + sc * 8]);
    }
    __syncthreads();
#pragma unroll
    for (int ks = 0; ks < 2; ++ks) {
      s16x8 af[2], bf[2];
      int kk = ks * 32 + 8 * (l >> 4);
#pragma unroll
      for (int i = 0; i < 2; ++i) {
        af[i] = *reinterpret_cast<const s16x8*>(&Als[wr * 32 + i * 16 + (l & 15)][kk]);
        bf[i] = *reinterpret_cast<const s16x8*>(&Bls[wc * 32 + i * 16 + (l & 15)][kk]);
      }
#pragma unroll
      for (int mi = 0; mi < 2; ++mi)
#pragma unroll
        for (int ni = 0; ni < 2; ++ni)
          acc[mi][ni] = __builtin_amdgcn_mfma_f32_16x16x32_bf16(af[mi], bf[ni], acc[mi][ni], 0, 0, 0);
    }
    __syncthreads();
  }
  int rq = l >> 4, cc = l & 15;
#pragma unroll
  for (int mi = 0; mi < 2; ++mi)
#pragma unroll
    for (int ni = 0; ni < 2; ++ni) {
      int n = n0 + wc * 32 + ni * 16 + cc;
      int mB = m0 + wr * 32 + mi * 16 + rq * 4;
#pragma unroll
      for (int r2 = 0; r2 < 4; ++r2) {
        int m = mB + r2;
        int b = m >> 11;
        int lb = m & (SEQ - 1);
        size_t addr = ((size_t)(b * DMODEL + n)) * SEQ + lb;
        out[addr] = acc[mi][ni][r2] + x[addr];
      }
    }
}

extern "C" void kernel_launch(void* const* d_in, const int* in_sizes, int n_in,
                              void* d_out, int out_size, void* d_ws, size_t ws_size,
                              hipStream_t stream) {
  const float* x          = (const float*)d_in[0];
  const float* norm_w     = (const float*)d_in[1];
  const float* in_proj_w  = (const float*)d_in[2];
  const float* conv_w     = (const float*)d_in[3];
  const float* conv_b     = (const float*)d_in[4];
  const float* x_proj_w   = (const float*)d_in[5];
  const float* dt_proj_w  = (const float*)d_in[6];
  const float* dt_proj_b  = (const float*)d_in[7];
  const float* A_log      = (const float*)d_in[8];
  const float* Dw         = (const float*)d_in[9];
  const float* out_proj_w = (const float*)d_in[10];
  float* out = (float*)d_out;
  float* ws  = (float*)d_ws;

  float* BCbuf  = ws + OFF_BC;
  ushort* Sbuf  = (ushort*)(ws + OFF_S);
  ushort* Hinit = (ushort*)(ws + OFF_H);
  float* anv    = ws + OFF_ANV;
  float* sumd   = ws + OFF_SD;
  ushort* ub   = (ushort*)(ws + OFF_US);
  ushort* wob  = ub + UOFF_WOB;
  ushort* xzb  = ub + UOFF_XZ;
  ushort* xcb  = ub + UOFF_XC;
  ushort* delt = ub + UOFF_DL;
  ushort* ygb  = ub + UOFF_YG;
  ushort* xpwb = ub + UOFF_XPW;
  ushort* dtwb = ub + UOFF_DTW;

  k_g1   <<<256,          256, 0, stream>>>(x, norm_w, in_proj_w, out_proj_w, x_proj_w, dt_proj_w,
                                            A_log, wob, xpwb, dtwb, anv, xzb);
  k_xps1 <<<256,          512, 0, stream>>>(xzb, conv_w, conv_b, xpwb, dtwb, dt_proj_b, anv,
                                            xcb, BCbuf, delt, Sbuf, sumd);
  k_comb <<<1024,         256, 0, stream>>>(sumd, Sbuf, anv, Hinit);
  k_scan2<<<512,          256, 0, stream>>>(delt, xcb, xzb, BCbuf, anv, Hinit, Dw, ygb);
  k_gemm3<<<dim3(64, 4),  256, 0, stream>>>(ygb, wob, x, out);
}

// Round 25
// 69.354 us; speedup vs baseline: 1.0485x; 1.0485x over previous
//
#include <hip/hip_runtime.h>
#include <hip/hip_bf16.h>
#include <math.h>

#define BATCH  2
#define SEQ    2048
#define DMODEL 256
#define DSTATE 16
#define DINNER 512
#define RTOT   4096
#define GCH    128
#define LCH    16
#define NW1    (2*DINNER*DMODEL)   // 262144
#define NW2    (DMODEL*DINNER)     // 131072
#define NXPW   (48*512)            // 24576
#define NDTW   (512*16)            // 8192

typedef float f32x4 __attribute__((ext_vector_type(4)));
typedef short s16x8 __attribute__((ext_vector_type(8)));

__device__ __forceinline__ float silu_f(float v){ return v / (1.f + __expf(-v)); }
__device__ __forceinline__ ushort f2bf(float f){
  __hip_bfloat16 h = __float2bfloat16(f);
  return *reinterpret_cast<ushort*>(&h);
}
__device__ __forceinline__ float bf2f(ushort u){
  union { unsigned int i; float f; } c; c.i = ((unsigned int)u) << 16; return c.f;
}

// ---- workspace layout (float offsets; S/H bf16 in fp32-sized slots) ----
#define OFF_BC   0
#define OFF_S    (OFF_BC + RTOT*32)          // Sbuf (bf16)
#define OFF_H    (OFF_S + 2*GCH*16*512)      // Hinit (bf16)
#define OFF_ANV  (OFF_H + 2*GCH*16*512)      // 16*512 fp32
#define OFF_SD   (OFF_ANV + 16*512)          // sumd fp32
#define OFF_US   (OFF_SD + 2*GCH*512)
#define UOFF_WOB ((size_t)0)
#define UOFF_XZ  (UOFF_WOB + (size_t)NW2)
#define UOFF_XC  (UOFF_XZ + (size_t)RTOT*1024)
#define UOFF_DL  (UOFF_XC + (size_t)RTOT*512)
#define UOFF_YG  (UOFF_DL + (size_t)RTOT*512)
#define UOFF_XPW (UOFF_YG + (size_t)RTOT*512)
#define UOFF_DTW (UOFF_XPW + (size_t)NXPW)

// ======== kernel 1: RMSNorm-into-LDS + B-panel cvt + GEMM1 (128x128) + cvt tails ========
__global__ __launch_bounds__(256) void k_g1(const float* __restrict__ x,
                                            const float* __restrict__ norm_w,
                                            const float* __restrict__ w_in,
                                            const float* __restrict__ w_out,
                                            const float* __restrict__ xpw,
                                            const float* __restrict__ dtw,
                                            const float* __restrict__ A_log,
                                            ushort* __restrict__ wob,
                                            ushort* __restrict__ xpwb,
                                            ushort* __restrict__ dtwb,
                                            float* __restrict__ anv,
                                            ushort* __restrict__ xzb){
  __shared__ ushort As[128][264];
  __shared__ ushort Bls[128][264];
  __shared__ float red[4][64];
  int bid = blockIdx.x;
  int t = threadIdx.x;
  // tails: out_proj cvt + xpw/dtw cvt + A-table
  {
    if (t < 128) {
      int base = bid * 512 + t * 4;
      float4 v = *reinterpret_cast<const float4*>(&w_out[base]);
      ushort4 o; o.x = f2bf(v.x); o.y = f2bf(v.y); o.z = f2bf(v.z); o.w = f2bf(v.w);
      *reinterpret_cast<ushort4*>(&wob[base]) = o;
    } else if (t < 160) {
      int base = (bid * 32 + (t - 128)) * 4;     // [0, 32768)
      if (base < NXPW) {
        float4 v = *reinterpret_cast<const float4*>(&xpw[base]);
        ushort4 o; o.x = f2bf(v.x); o.y = f2bf(v.y); o.z = f2bf(v.z); o.w = f2bf(v.w);
        *reinterpret_cast<ushort4*>(&xpwb[base]) = o;
      } else {
        int j = base - NXPW;
        float4 v = *reinterpret_cast<const float4*>(&dtw[j]);
        ushort4 o; o.x = f2bf(v.x); o.y = f2bf(v.y); o.z = f2bf(v.z); o.w = f2bf(v.w);
        *reinterpret_cast<ushort4*>(&dtwb[j]) = o;
      }
    }
    if (bid < 32) {
      int e = bid * 256 + t;           // e = n*512 + d
      int n = e >> 9, d = e & 511;
      anv[e] = -__expf(A_log[d * 16 + n]);
    }
  }
  int mB = bid >> 3, nB = bid & 7;
  int m0 = mB * 128, n0 = nB * 128;
  int b = mB >> 4;
  int l0 = (mB & 15) << 7;
  const float* xb = x + (size_t)b * DMODEL * SEQ;
  int ll = t & 63, cq = t >> 6;
  // ---- RMSNorm into As (two 64-row halves) ----
  for (int half = 0; half < 2; ++half) {
    int l = l0 + half * 64 + ll;
    float ss = 0.f;
    for (int it = 0; it < 64; ++it) {
      int c = cq * 64 + it;
      float v = xb[(size_t)c * SEQ + l];
      ss += v * v;
    }
    red[cq][ll] = ss;
    __syncthreads();
    float s = red[0][ll] + red[1][ll] + red[2][ll] + red[3][ll];
    float r = rsqrtf(s * (1.f / DMODEL) + 1e-5f);
    for (int it = 0; it < 64; ++it) {
      int c = cq * 64 + it;
      float v = xb[(size_t)c * SEQ + l];
      As[half * 64 + ll][c] = f2bf(v * r * norm_w[c]);
    }
    __syncthreads();
  }
  // ---- B-panel cvt into Bls ----
  {
    int r = t >> 1, ch = t & 1;
    const float* wr_ = &w_in[(size_t)(n0 + r) * DMODEL + ch * 128];
#pragma unroll
    for (int j = 0; j < 32; ++j) {
      float4 v = *reinterpret_cast<const float4*>(&wr_[j * 4]);
      ushort4 o; o.x = f2bf(v.x); o.y = f2bf(v.y); o.z = f2bf(v.z); o.w = f2bf(v.w);
      *reinterpret_cast<ushort4*>(&Bls[r][ch * 128 + j * 4]) = o;
    }
  }
  __syncthreads();
  // ---- GEMM from LDS (K=256) ----
  int w = t >> 6, l = t & 63;
  int wr = w >> 1, wc = w & 1;
  f32x4 acc[4][4] = {};
#pragma unroll
  for (int ks = 0; ks < 8; ++ks) {
    int kk = ks * 32 + 8 * (l >> 4);
    s16x8 af[4], bf[4];
#pragma unroll
    for (int i = 0; i < 4; ++i) {
      af[i] = *reinterpret_cast<const s16x8*>(&As[wr * 64 + i * 16 + (l & 15)][kk]);
      bf[i] = *reinterpret_cast<const s16x8*>(&Bls[wc * 64 + i * 16 + (l & 15)][kk]);
    }
#pragma unroll
    for (int mi = 0; mi < 4; ++mi)
#pragma unroll
      for (int ni = 0; ni < 4; ++ni)
        acc[mi][ni] = __builtin_amdgcn_mfma_f32_16x16x32_bf16(af[mi], bf[ni], acc[mi][ni], 0, 0, 0);
  }
  int rq = l >> 4, cc = l & 15;
#pragma unroll
  for (int mi = 0; mi < 4; ++mi)
#pragma unroll
    for (int ni = 0; ni < 4; ++ni) {
      int n = n0 + wc * 64 + ni * 16 + cc;
      int mB2 = m0 + wr * 64 + mi * 16 + rq * 4;
#pragma unroll
      for (int r2 = 0; r2 < 4; ++r2)
        xzb[(size_t)(mB2 + r2) * 1024 + n] = f2bf(acc[mi][ni][r2]);
    }
}

// ======== kernel 2: FUSED conv + x_proj + dt_proj + scan1 (256 blocks x 512 threads) ========
__global__ __launch_bounds__(512, 4) void k_xps1(const ushort* __restrict__ xzb,
                                                 const float* __restrict__ conv_w,
                                                 const float* __restrict__ conv_b,
                                                 const ushort* __restrict__ xpwb,  // [48][512]
                                                 const ushort* __restrict__ dtwb,  // [512][16]
                                                 const float* __restrict__ dtb,
                                                 const float* __restrict__ anv,
                                                 ushort* __restrict__ xcb,
                                                 float* __restrict__ BCbuf,
                                                 ushort* __restrict__ delt,
                                                 ushort* __restrict__ Sbuf,
                                                 float* __restrict__ sumd){
  __shared__ ushort xcs[16][520];      // conv+silu output (bf16), all 512 d
  __shared__ float red[8][3][256];     // x_proj per-wave partials (8 waves)
  __shared__ ushort dts_s[16][40];     // dt pre-acts (K-pad to 32 with zeros)
  __shared__ float bcs[16][32];        // B,C per row
  __shared__ ushort dl_s[16][520];     // delta, all 512 d
  int chunk = blockIdx.x;              // [0,256)
  int b = chunk >> 7;
  int base = chunk * 16;               // == b*SEQ + g*16
  int l0 = (chunk & 127) * 16;
  int t = threadIdx.x;                 // [0,512)
  int w = t >> 6, l = t & 63;
  int rq = l >> 4, cc = l & 15;
  // zero ALL 384 pad slots (rows 0..15, cols 16..39)
  if (t < 384) dts_s[t / 24][16 + t % 24] = 0;
  // ---- conv + SiLU: thread owns d = t (single column) ----
  {
    int d0 = t;
    ushort xv[19];
#pragma unroll
    for (int rr = 0; rr < 19; ++rr) {
      ushort v = 0;
      int ls = l0 - 3 + rr;
      if (ls >= 0)
        v = xzb[((size_t)(b * SEQ + ls)) * 1024 + d0];
      xv[rr] = v;
    }
    float4 cw = *reinterpret_cast<const float4*>(&conv_w[d0 * 4]);
    float bb = conv_b[d0];
#pragma unroll
    for (int r = 0; r < 16; ++r) {
      float a = bb;
      a += bf2f(xv[r + 0]) * cw.x;
      a += bf2f(xv[r + 1]) * cw.y;
      a += bf2f(xv[r + 2]) * cw.z;
      a += bf2f(xv[r + 3]) * cw.w;
      ushort o = f2bf(silu_f(a));
      xcs[r][d0] = o;
      xcb[((size_t)(base + r)) * 512 + d0] = o;
    }
  }
  __syncthreads();
  // ---- x_proj: M=16 N=48 K=512, K-split across 8 waves (64 each) ----
  {
    f32x4 acc[3] = {};
#pragma unroll
    for (int ks = 0; ks < 2; ++ks) {
      int kk = w * 64 + ks * 32 + 8 * rq;
      s16x8 af = *reinterpret_cast<const s16x8*>(&xcs[cc][kk]);
#pragma unroll
      for (int ni = 0; ni < 3; ++ni) {
        s16x8 bf = *reinterpret_cast<const s16x8*>(&xpwb[(size_t)(ni * 16 + cc) * 512 + kk]);
        acc[ni] = __builtin_amdgcn_mfma_f32_16x16x32_bf16(af, bf, acc[ni], 0, 0, 0);
      }
    }
#pragma unroll
    for (int ni = 0; ni < 3; ++ni)
      *reinterpret_cast<f32x4*>(&red[w][ni][l * 4]) = acc[ni];
  }
  __syncthreads();
  // ---- reduce 8 K-partials -> dts_s (bf16), bcs LDS, BCbuf global ----
  if (t < 192) {
    int ni = t >> 6, lr = t & 63;
    f32x4 s = *reinterpret_cast<const f32x4*>(&red[0][ni][lr * 4]);
#pragma unroll
    for (int ww = 1; ww < 8; ++ww)
      s += *reinterpret_cast<const f32x4*>(&red[ww][ni][lr * 4]);
    int rr = lr >> 4, nc = lr & 15;
#pragma unroll
    for (int r2 = 0; r2 < 4; ++r2) {
      int row = rr * 4 + r2;
      if (ni == 0) dts_s[row][nc] = f2bf(s[r2]);
      else {
        bcs[row][(ni - 1) * 16 + nc] = s[r2];
        BCbuf[(size_t)(base + row) * 32 + (ni - 1) * 16 + nc] = s[r2];
      }
    }
  }
  __syncthreads();
  // ---- dt_proj: M=16, N=512 (64 per wave), K=32 (16 real) + softplus ----
  {
    int kk2 = 8 * rq;
    s16x8 af2 = *reinterpret_cast<const s16x8*>(&dts_s[cc][kk2]);
    f32x4 acc2[4] = {};
#pragma unroll
    for (int ni = 0; ni < 4; ++ni) {
      s16x8 bf2 = {0, 0, 0, 0, 0, 0, 0, 0};
      if (kk2 < 16) {
        int dglob = w * 64 + ni * 16 + cc;
        bf2 = *reinterpret_cast<const s16x8*>(&dtwb[dglob * 16 + kk2]);
      }
      acc2[ni] = __builtin_amdgcn_mfma_f32_16x16x32_bf16(af2, bf2, acc2[ni], 0, 0, 0);
    }
#pragma unroll
    for (int ni = 0; ni < 4; ++ni) {
      int dglob = w * 64 + ni * 16 + cc;
      float bias = dtb[dglob];
#pragma unroll
      for (int r2 = 0; r2 < 4; ++r2) {
        int row = rq * 4 + r2;
        float s = acc2[ni][r2] + bias;
        float sp = (s > 15.f) ? s : log1pf(__expf(s));
        ushort u = f2bf(sp);
        dl_s[row][dglob] = u;
        delt[(size_t)(base + row) * 512 + dglob] = u;
      }
    }
  }
  __syncthreads();
  // ---- scan pass 1 from LDS -> Sbuf (bf16), sumd; thread owns d = t ----
  {
    int d = t;
    float an[16], h[16];
#pragma unroll
    for (int n = 0; n < 16; ++n) { an[n] = anv[n * 512 + d]; h[n] = 0.f; }
    float sd = 0.f;
    for (int s = 0; s < LCH; ++s) {
      float dl = bf2f(dl_s[s][d]);
      float xv = bf2f(xcs[s][d]);
      float dx = dl * xv;
      sd += dl;
#pragma unroll
      for (int n = 0; n < 16; ++n) {
        float dA = __expf(dl * an[n]);
        h[n] = dA * h[n] + dx * bcs[s][n];
      }
    }
    sumd[(size_t)chunk * 512 + d] = sd;
#pragma unroll
    for (int n = 0; n < 16; ++n)
      Sbuf[((size_t)chunk * 16 + n) * 512 + d] = f2bf(h[n]);
  }
}

// ======== kernel 3: chunk combine -> Hinit bf16 (1024 blocks, 16-wide d) ========
__global__ __launch_bounds__(256) void k_comb(const float* __restrict__ sumd,
                                              const ushort* __restrict__ Sbuf,
                                              const float* __restrict__ anv,
                                              ushort* __restrict__ Hinit){
  __shared__ float PL[16 * 16];
  __shared__ float SL[16 * 16];
  int bid = blockIdx.x;            // 1024 = b(1) n(4) d0(5)
  int b = bid >> 9, n = (bid >> 5) & 15, d0 = (bid & 31) * 16;
  int t = threadIdx.x;
  int j = t >> 4, dl = t & 15;     // 16 segments x 16 d
  int d = d0 + dl;
  float an = anv[n * 512 + d];
  float Pa[8], Sa[8];
  float P = 1.f, S = 0.f;
#pragma unroll
  for (int i = 0; i < 8; ++i) {
    int c = b * GCH + j * 8 + i;
    float sd = sumd[(size_t)c * 512 + d];
    float p = __expf(an * sd);
    float s = bf2f(Sbuf[((size_t)c * 16 + n) * 512 + d]);
    Pa[i] = p; Sa[i] = s;
    S = p * S + s; P *= p;
  }
  PL[j * 16 + dl] = P; SL[j * 16 + dl] = S;
  __syncthreads();
  if (t < 16) {
    float hp = 0.f;
    for (int jj = 0; jj < 16; ++jj) {
      float p = PL[jj * 16 + t], s = SL[jj * 16 + t];
      SL[jj * 16 + t] = hp;
      hp = p * hp + s;
    }
  }
  __syncthreads();
  float h = SL[j * 16 + dl];
#pragma unroll
  for (int i = 0; i < 8; ++i) {
    int c = b * GCH + j * 8 + i;
    Hinit[((size_t)c * 16 + n) * 512 + d] = f2bf(h);
    h = Pa[i] * h + Sa[i];
  }
}

// ======== kernel 4: scan pass 2 with LDS-staged tiles (512 blocks, 4 blocks/CU) ========
__global__ __launch_bounds__(256, 4) void k_scan2(const ushort* __restrict__ deltab,
                                                  const ushort* __restrict__ xcb,
                                                  const ushort* __restrict__ xzb,
                                                  const float* __restrict__ BCbuf,
                                                  const float* __restrict__ anv,
                                                  const ushort* __restrict__ Hinit,
                                                  const float* __restrict__ Dw,
                                                  ushort* __restrict__ ygb){
  __shared__ ushort dl_s[16][260];
  __shared__ ushort xc_s[16][260];
  __shared__ ushort z_s [16][260];
  __shared__ float bcs[LCH][32];
  int bid = blockIdx.x;
  int b = bid >> 8;
  int g = (bid >> 1) & 127;
  int dh = bid & 1;
  int t = threadIdx.x;
  int d = dh * 256 + t;
  int base = b * SEQ + g * LCH;
  // ---- coalesced staging: 3 tiles x 512 int4-slots, 6 loads/thread ----
#pragma unroll
  for (int i = 0; i < 6; ++i) {
    int slot = i * 256 + t;            // [0,1536)
    int tile = slot >> 9;              // 0:delta 1:xc 2:z
    int idx = slot & 511;
    int row = idx >> 5, c16 = idx & 31;
    int col = dh * 256 + c16 * 8;
    size_t grow = (size_t)(base + row);
    int4 v;
    if (tile == 0)      v = *reinterpret_cast<const int4*>(&deltab[grow * 512 + col]);
    else if (tile == 1) v = *reinterpret_cast<const int4*>(&xcb[grow * 512 + col]);
    else                v = *reinterpret_cast<const int4*>(&xzb[grow * 1024 + 512 + col]);
    ushort (*dst)[260] = (tile == 0) ? dl_s : (tile == 1) ? xc_s : z_s;
    *reinterpret_cast<int4*>(&dst[row][c16 * 8]) = v;
  }
  {
    float2 v = *reinterpret_cast<const float2*>(&BCbuf[(size_t)base * 32 + t * 2]);
    *reinterpret_cast<float2*>(&((float*)bcs)[t * 2]) = v;
  }
  __syncthreads();
  float an[16], h[16];
  size_t hb0 = ((size_t)(b * GCH + g) * 16) * 512 + d;
#pragma unroll
  for (int n = 0; n < 16; ++n) { an[n] = anv[n * 512 + d]; h[n] = bf2f(Hinit[hb0 + (size_t)n * 512]); }
  float Dd = Dw[d];
  for (int s = 0; s < LCH; ++s) {
    float dl = bf2f(dl_s[s][t]);
    float xv = bf2f(xc_s[s][t]);
    float dx = dl * xv;
    float y = 0.f;
#pragma unroll
    for (int n = 0; n < 16; ++n) {
      float dA = __expf(dl * an[n]);
      h[n] = dA * h[n] + dx * bcs[s][n];
      y += h[n] * bcs[s][16 + n];
    }
    float zg = silu_f(bf2f(z_s[s][t]));
    ygb[(size_t)(base + s) * 512 + d] = f2bf((y + xv * Dd) * zg);
  }
}

// ======== kernel 5: GEMM3 64x64 tiles (256 blocks) out = residual + yg.Wout^T ========
__global__ __launch_bounds__(256) void k_gemm3(const ushort* __restrict__ A,
                                               const ushort* __restrict__ B,
                                               const float* __restrict__ x,
                                               float* __restrict__ out){
  __shared__ ushort Als[64][72];
  __shared__ ushort Bls[64][72];
  int m0 = blockIdx.x * 64, n0 = blockIdx.y * 64;
  int t = threadIdx.x;
  int w = t >> 6, l = t & 63;
  int wr = w >> 1, wc = w & 1;
  f32x4 acc[2][2] = {};
  int sr = t >> 3, sc = t & 7;
  for (int k0 = 0; k0 < DINNER; k0 += 64) {
#pragma unroll
    for (int p = 0; p < 2; ++p) {
      int r = sr + p * 32;
      *reinterpret_cast<int4*>(&Als[r][sc * 8]) =
        *reinterpret_cast<const int4*>(&A[((size_t)(m0 + r)) * DINNER + k0 + sc * 8]);
      *reinterpret_cast<int4*>(&Bls[r][sc * 8]) =
        *reinterpret_cast<const int4*>(&B[((size_t)(n0 + r)) * DINNER + k0 + sc * 8]);
    }
    __syncthreads();
#pragma unroll
    for (int ks = 0; ks < 2; ++ks) {
      s16x8 af[2], bf[2];
      int kk = ks * 32 + 8 * (l >> 4);
#pragma unroll
      for (int i = 0; i < 2; ++i) {
        af[i] = *reinterpret_cast<const s16x8*>(&Als[wr * 32 + i * 16 + (l & 15)][kk]);
        bf[i] = *reinterpret_cast<const s16x8*>(&Bls[wc * 32 + i * 16 + (l & 15)][kk]);
      }
#pragma unroll
      for (int mi = 0; mi < 2; ++mi)
#pragma unroll
        for (int ni = 0; ni < 2; ++ni)
          acc[mi][ni] = __builtin_amdgcn_mfma_f32_16x16x32_bf16(af[mi], bf[ni], acc[mi][ni], 0, 0, 0);
    }
    __syncthreads();
  }
  int rq = l >> 4, cc = l & 15;
#pragma unroll
  for (int mi = 0; mi < 2; ++mi)
#pragma unroll
    for (int ni = 0; ni < 2; ++ni) {
      int n = n0 + wc * 32 + ni * 16 + cc;
      int mB = m0 + wr * 32 + mi * 16 + rq * 4;
#pragma unroll
      for (int r2 = 0; r2 < 4; ++r2) {
        int m = mB + r2;
        int b = m >> 11;
        int lb = m & (SEQ - 1);
        size_t addr = ((size_t)(b * DMODEL + n)) * SEQ + lb;
        out[addr] = acc[mi][ni][r2] + x[addr];
      }
    }
}

extern "C" void kernel_launch(void* const* d_in, const int* in_sizes, int n_in,
                              void* d_out, int out_size, void* d_ws, size_t ws_size,
                              hipStream_t stream) {
  const float* x          = (const float*)d_in[0];
  const float* norm_w     = (const float*)d_in[1];
  const float* in_proj_w  = (const float*)d_in[2];
  const float* conv_w     = (const float*)d_in[3];
  const float* conv_b     = (const float*)d_in[4];
  const float* x_proj_w   = (const float*)d_in[5];
  const float* dt_proj_w  = (const float*)d_in[6];
  const float* dt_proj_b  = (const float*)d_in[7];
  const float* A_log      = (const float*)d_in[8];
  const float* Dw         = (const float*)d_in[9];
  const float* out_proj_w = (const float*)d_in[10];
  float* out = (float*)d_out;
  float* ws  = (float*)d_ws;

  float* BCbuf  = ws + OFF_BC;
  ushort* Sbuf  = (ushort*)(ws + OFF_S);
  ushort* Hinit = (ushort*)(ws + OFF_H);
  float* anv    = ws + OFF_ANV;
  float* sumd   = ws + OFF_SD;
  ushort* ub   = (ushort*)(ws + OFF_US);
  ushort* wob  = ub + UOFF_WOB;
  ushort* xzb  = ub + UOFF_XZ;
  ushort* xcb  = ub + UOFF_XC;
  ushort* delt = ub + UOFF_DL;
  ushort* ygb  = ub + UOFF_YG;
  ushort* xpwb = ub + UOFF_XPW;
  ushort* dtwb = ub + UOFF_DTW;

  k_g1   <<<256,          256, 0, stream>>>(x, norm_w, in_proj_w, out_proj_w, x_proj_w, dt_proj_w,
                                            A_log, wob, xpwb, dtwb, anv, xzb);
  k_xps1 <<<256,          512, 0, stream>>>(xzb, conv_w, conv_b, xpwb, dtwb, dt_proj_b, anv,
                                            xcb, BCbuf, delt, Sbuf, sumd);
  k_comb <<<1024,         256, 0, stream>>>(sumd, Sbuf, anv, Hinit);
  k_scan2<<<512,          256, 0, stream>>>(delt, xcb, xzb, BCbuf, anv, Hinit, Dw, ygb);
  k_gemm3<<<dim3(64, 4),  256, 0, stream>>>(ygb, wob, x, out);
}

// Round 26
// 67.945 us; speedup vs baseline: 1.0702x; 1.0207x over previous
//
#include <hip/hip_runtime.h>
#include <hip/hip_bf16.h>
#include <math.h>

#define BATCH  2
#define SEQ    2048
#define DMODEL 256
#define DSTATE 16
#define DINNER 512
#define RTOT   4096
#define GCH    128
#define LCH    16
#define NW1    (2*DINNER*DMODEL)   // 262144
#define NW2    (DMODEL*DINNER)     // 131072
#define NXPW   (48*512)            // 24576
#define NDTW   (512*16)            // 8192

typedef float f32x4 __attribute__((ext_vector_type(4)));
typedef short s16x8 __attribute__((ext_vector_type(8)));

__device__ __forceinline__ float silu_f(float v){ return v / (1.f + __expf(-v)); }
__device__ __forceinline__ ushort f2bf(float f){
  __hip_bfloat16 h = __float2bfloat16(f);
  return *reinterpret_cast<ushort*>(&h);
}
__device__ __forceinline__ float bf2f(ushort u){
  union { unsigned int i; float f; } c; c.i = ((unsigned int)u) << 16; return c.f;
}

// ---- workspace layout (float offsets; S/H bf16 in fp32-sized slots) ----
#define OFF_BC   0
#define OFF_S    (OFF_BC + RTOT*32)          // Sbuf (bf16)
#define OFF_H    (OFF_S + 2*GCH*16*512)      // Hinit (bf16)
#define OFF_ANV  (OFF_H + 2*GCH*16*512)      // 16*512 fp32
#define OFF_SD   (OFF_ANV + 16*512)          // sumd fp32
#define OFF_US   (OFF_SD + 2*GCH*512)
#define UOFF_WOB ((size_t)0)
#define UOFF_XZ  (UOFF_WOB + (size_t)NW2)
#define UOFF_XC  (UOFF_XZ + (size_t)RTOT*1024)
#define UOFF_DL  (UOFF_XC + (size_t)RTOT*512)
#define UOFF_YG  (UOFF_DL + (size_t)RTOT*512)
#define UOFF_XPW (UOFF_YG + (size_t)RTOT*512)
#define UOFF_DTW (UOFF_XPW + (size_t)NXPW)

// ======== kernel 1: RMSNorm-into-LDS (register-buffered single x pass) + B-panel cvt + GEMM1 ========
__global__ __launch_bounds__(256) void k_g1(const float* __restrict__ x,
                                            const float* __restrict__ norm_w,
                                            const float* __restrict__ w_in,
                                            const float* __restrict__ w_out,
                                            const float* __restrict__ xpw,
                                            const float* __restrict__ dtw,
                                            const float* __restrict__ A_log,
                                            ushort* __restrict__ wob,
                                            ushort* __restrict__ xpwb,
                                            ushort* __restrict__ dtwb,
                                            float* __restrict__ anv,
                                            ushort* __restrict__ xzb){
  __shared__ ushort As[128][264];
  __shared__ ushort Bls[128][264];
  __shared__ float red[4][64];
  int bid = blockIdx.x;
  int t = threadIdx.x;
  // tails: out_proj cvt + xpw/dtw cvt + A-table
  {
    if (t < 128) {
      int base = bid * 512 + t * 4;
      float4 v = *reinterpret_cast<const float4*>(&w_out[base]);
      ushort4 o; o.x = f2bf(v.x); o.y = f2bf(v.y); o.z = f2bf(v.z); o.w = f2bf(v.w);
      *reinterpret_cast<ushort4*>(&wob[base]) = o;
    } else if (t < 160) {
      int base = (bid * 32 + (t - 128)) * 4;     // [0, 32768)
      if (base < NXPW) {
        float4 v = *reinterpret_cast<const float4*>(&xpw[base]);
        ushort4 o; o.x = f2bf(v.x); o.y = f2bf(v.y); o.z = f2bf(v.z); o.w = f2bf(v.w);
        *reinterpret_cast<ushort4*>(&xpwb[base]) = o;
      } else {
        int j = base - NXPW;
        float4 v = *reinterpret_cast<const float4*>(&dtw[j]);
        ushort4 o; o.x = f2bf(v.x); o.y = f2bf(v.y); o.z = f2bf(v.z); o.w = f2bf(v.w);
        *reinterpret_cast<ushort4*>(&dtwb[j]) = o;
      }
    }
    if (bid < 32) {
      int e = bid * 256 + t;           // e = n*512 + d
      int n = e >> 9, d = e & 511;
      anv[e] = -__expf(A_log[d * 16 + n]);
    }
  }
  int mB = bid >> 3, nB = bid & 7;
  int m0 = mB * 128, n0 = nB * 128;
  int b = mB >> 4;
  int l0 = (mB & 15) << 7;
  const float* xb = x + (size_t)b * DMODEL * SEQ;
  int ll = t & 63, cq = t >> 6;
  // ---- RMSNorm into As: single global pass, values held in registers ----
  for (int half = 0; half < 2; ++half) {
    int l = l0 + half * 64 + ll;
    float vv[64];
    float ss = 0.f;
#pragma unroll
    for (int it = 0; it < 64; ++it) {
      int c = cq * 64 + it;
      float v = xb[(size_t)c * SEQ + l];
      vv[it] = v;
      ss += v * v;
    }
    red[cq][ll] = ss;
    __syncthreads();
    float s = red[0][ll] + red[1][ll] + red[2][ll] + red[3][ll];
    float r = rsqrtf(s * (1.f / DMODEL) + 1e-5f);
#pragma unroll
    for (int it = 0; it < 64; ++it) {
      int c = cq * 64 + it;
      As[half * 64 + ll][c] = f2bf(vv[it] * r * norm_w[c]);
    }
    __syncthreads();
  }
  // ---- B-panel cvt into Bls ----
  {
    int r = t >> 1, ch = t & 1;
    const float* wr_ = &w_in[(size_t)(n0 + r) * DMODEL + ch * 128];
#pragma unroll
    for (int j = 0; j < 32; ++j) {
      float4 v = *reinterpret_cast<const float4*>(&wr_[j * 4]);
      ushort4 o; o.x = f2bf(v.x); o.y = f2bf(v.y); o.z = f2bf(v.z); o.w = f2bf(v.w);
      *reinterpret_cast<ushort4*>(&Bls[r][ch * 128 + j * 4]) = o;
    }
  }
  __syncthreads();
  // ---- GEMM from LDS (K=256) ----
  int w = t >> 6, l = t & 63;
  int wr = w >> 1, wc = w & 1;
  f32x4 acc[4][4] = {};
#pragma unroll
  for (int ks = 0; ks < 8; ++ks) {
    int kk = ks * 32 + 8 * (l >> 4);
    s16x8 af[4], bf[4];
#pragma unroll
    for (int i = 0; i < 4; ++i) {
      af[i] = *reinterpret_cast<const s16x8*>(&As[wr * 64 + i * 16 + (l & 15)][kk]);
      bf[i] = *reinterpret_cast<const s16x8*>(&Bls[wc * 64 + i * 16 + (l & 15)][kk]);
    }
#pragma unroll
    for (int mi = 0; mi < 4; ++mi)
#pragma unroll
      for (int ni = 0; ni < 4; ++ni)
        acc[mi][ni] = __builtin_amdgcn_mfma_f32_16x16x32_bf16(af[mi], bf[ni], acc[mi][ni], 0, 0, 0);
  }
  int rq = l >> 4, cc = l & 15;
#pragma unroll
  for (int mi = 0; mi < 4; ++mi)
#pragma unroll
    for (int ni = 0; ni < 4; ++ni) {
      int n = n0 + wc * 64 + ni * 16 + cc;
      int mB2 = m0 + wr * 64 + mi * 16 + rq * 4;
#pragma unroll
      for (int r2 = 0; r2 < 4; ++r2)
        xzb[(size_t)(mB2 + r2) * 1024 + n] = f2bf(acc[mi][ni][r2]);
    }
}

// ======== kernel 2: FUSED conv + x_proj + dt_proj + scan1 (256 blocks x 512 threads) ========
__global__ __launch_bounds__(512, 4) void k_xps1(const ushort* __restrict__ xzb,
                                                 const float* __restrict__ conv_w,
                                                 const float* __restrict__ conv_b,
                                                 const ushort* __restrict__ xpwb,  // [48][512]
                                                 const ushort* __restrict__ dtwb,  // [512][16]
                                                 const float* __restrict__ dtb,
                                                 const float* __restrict__ anv,
                                                 ushort* __restrict__ xcb,
                                                 float* __restrict__ BCbuf,
                                                 ushort* __restrict__ delt,
                                                 ushort* __restrict__ Sbuf,
                                                 float* __restrict__ sumd){
  __shared__ ushort xcs[16][520];      // conv+silu output (bf16), all 512 d
  __shared__ float red[8][3][256];     // x_proj per-wave partials (8 waves)
  __shared__ ushort dts_s[16][40];     // dt pre-acts (K-pad to 32 with zeros)
  __shared__ float bcs[16][32];        // B,C per row
  __shared__ ushort dl_s[16][520];     // delta, all 512 d
  int chunk = blockIdx.x;              // [0,256)
  int b = chunk >> 7;
  int base = chunk * 16;               // == b*SEQ + g*16
  int l0 = (chunk & 127) * 16;
  int t = threadIdx.x;                 // [0,512)
  int w = t >> 6, l = t & 63;
  int rq = l >> 4, cc = l & 15;
  // zero ALL 384 pad slots (rows 0..15, cols 16..39)
  if (t < 384) dts_s[t / 24][16 + t % 24] = 0;
  // ---- conv + SiLU: thread owns d = t (single column) ----
  {
    int d0 = t;
    ushort xv[19];
#pragma unroll
    for (int rr = 0; rr < 19; ++rr) {
      ushort v = 0;
      int ls = l0 - 3 + rr;
      if (ls >= 0)
        v = xzb[((size_t)(b * SEQ + ls)) * 1024 + d0];
      xv[rr] = v;
    }
    float4 cw = *reinterpret_cast<const float4*>(&conv_w[d0 * 4]);
    float bb = conv_b[d0];
#pragma unroll
    for (int r = 0; r < 16; ++r) {
      float a = bb;
      a += bf2f(xv[r + 0]) * cw.x;
      a += bf2f(xv[r + 1]) * cw.y;
      a += bf2f(xv[r + 2]) * cw.z;
      a += bf2f(xv[r + 3]) * cw.w;
      ushort o = f2bf(silu_f(a));
      xcs[r][d0] = o;
      xcb[((size_t)(base + r)) * 512 + d0] = o;
    }
  }
  __syncthreads();
  // ---- x_proj: M=16 N=48 K=512, K-split across 8 waves (64 each) ----
  {
    f32x4 acc[3] = {};
#pragma unroll
    for (int ks = 0; ks < 2; ++ks) {
      int kk = w * 64 + ks * 32 + 8 * rq;
      s16x8 af = *reinterpret_cast<const s16x8*>(&xcs[cc][kk]);
#pragma unroll
      for (int ni = 0; ni < 3; ++ni) {
        s16x8 bf = *reinterpret_cast<const s16x8*>(&xpwb[(size_t)(ni * 16 + cc) * 512 + kk]);
        acc[ni] = __builtin_amdgcn_mfma_f32_16x16x32_bf16(af, bf, acc[ni], 0, 0, 0);
      }
    }
#pragma unroll
    for (int ni = 0; ni < 3; ++ni)
      *reinterpret_cast<f32x4*>(&red[w][ni][l * 4]) = acc[ni];
  }
  __syncthreads();
  // ---- reduce 8 K-partials -> dts_s (bf16), bcs LDS, BCbuf global ----
  if (t < 192) {
    int ni = t >> 6, lr = t & 63;
    f32x4 s = *reinterpret_cast<const f32x4*>(&red[0][ni][lr * 4]);
#pragma unroll
    for (int ww = 1; ww < 8; ++ww)
      s += *reinterpret_cast<const f32x4*>(&red[ww][ni][lr * 4]);
    int rr = lr >> 4, nc = lr & 15;
#pragma unroll
    for (int r2 = 0; r2 < 4; ++r2) {
      int row = rr * 4 + r2;
      if (ni == 0) dts_s[row][nc] = f2bf(s[r2]);
      else {
        bcs[row][(ni - 1) * 16 + nc] = s[r2];
        BCbuf[(size_t)(base + row) * 32 + (ni - 1) * 16 + nc] = s[r2];
      }
    }
  }
  __syncthreads();
  // ---- dt_proj: M=16, N=512 (64 per wave), K=32 (16 real) + softplus ----
  {
    int kk2 = 8 * rq;
    s16x8 af2 = *reinterpret_cast<const s16x8*>(&dts_s[cc][kk2]);
    f32x4 acc2[4] = {};
#pragma unroll
    for (int ni = 0; ni < 4; ++ni) {
      s16x8 bf2 = {0, 0, 0, 0, 0, 0, 0, 0};
      if (kk2 < 16) {
        int dglob = w * 64 + ni * 16 + cc;
        bf2 = *reinterpret_cast<const s16x8*>(&dtwb[dglob * 16 + kk2]);
      }
      acc2[ni] = __builtin_amdgcn_mfma_f32_16x16x32_bf16(af2, bf2, acc2[ni], 0, 0, 0);
    }
#pragma unroll
    for (int ni = 0; ni < 4; ++ni) {
      int dglob = w * 64 + ni * 16 + cc;
      float bias = dtb[dglob];
#pragma unroll
      for (int r2 = 0; r2 < 4; ++r2) {
        int row = rq * 4 + r2;
        float s = acc2[ni][r2] + bias;
        float sp = (s > 15.f) ? s : log1pf(__expf(s));
        ushort u = f2bf(sp);
        dl_s[row][dglob] = u;
        delt[(size_t)(base + row) * 512 + dglob] = u;
      }
    }
  }
  __syncthreads();
  // ---- scan pass 1 from LDS -> Sbuf (bf16), sumd; thread owns d = t ----
  {
    int d = t;
    float an[16], h[16];
#pragma unroll
    for (int n = 0; n < 16; ++n) { an[n] = anv[n * 512 + d]; h[n] = 0.f; }
    float sd = 0.f;
    for (int s = 0; s < LCH; ++s) {
      float dl = bf2f(dl_s[s][d]);
      float xv = bf2f(xcs[s][d]);
      float dx = dl * xv;
      sd += dl;
#pragma unroll
      for (int n = 0; n < 16; ++n) {
        float dA = __expf(dl * an[n]);
        h[n] = dA * h[n] + dx * bcs[s][n];
      }
    }
    sumd[(size_t)chunk * 512 + d] = sd;
#pragma unroll
    for (int n = 0; n < 16; ++n)
      Sbuf[((size_t)chunk * 16 + n) * 512 + d] = f2bf(h[n]);
  }
}

// ======== kernel 3: chunk combine -> Hinit bf16 (1024 blocks, 16-wide d) ========
__global__ __launch_bounds__(256) void k_comb(const float* __restrict__ sumd,
                                              const ushort* __restrict__ Sbuf,
                                              const float* __restrict__ anv,
                                              ushort* __restrict__ Hinit){
  __shared__ float PL[16 * 16];
  __shared__ float SL[16 * 16];
  int bid = blockIdx.x;            // 1024 = b(1) n(4) d0(5)
  int b = bid >> 9, n = (bid >> 5) & 15, d0 = (bid & 31) * 16;
  int t = threadIdx.x;
  int j = t >> 4, dl = t & 15;     // 16 segments x 16 d
  int d = d0 + dl;
  float an = anv[n * 512 + d];
  float Pa[8], Sa[8];
  float P = 1.f, S = 0.f;
#pragma unroll
  for (int i = 0; i < 8; ++i) {
    int c = b * GCH + j * 8 + i;
    float sd = sumd[(size_t)c * 512 + d];
    float p = __expf(an * sd);
    float s = bf2f(Sbuf[((size_t)c * 16 + n) * 512 + d]);
    Pa[i] = p; Sa[i] = s;
    S = p * S + s; P *= p;
  }
  PL[j * 16 + dl] = P; SL[j * 16 + dl] = S;
  __syncthreads();
  if (t < 16) {
    float hp = 0.f;
    for (int jj = 0; jj < 16; ++jj) {
      float p = PL[jj * 16 + t], s = SL[jj * 16 + t];
      SL[jj * 16 + t] = hp;
      hp = p * hp + s;
    }
  }
  __syncthreads();
  float h = SL[j * 16 + dl];
#pragma unroll
  for (int i = 0; i < 8; ++i) {
    int c = b * GCH + j * 8 + i;
    Hinit[((size_t)c * 16 + n) * 512 + d] = f2bf(h);
    h = Pa[i] * h + Sa[i];
  }
}

// ======== kernel 4: scan pass 2 with LDS-staged tiles (512 blocks, 4 blocks/CU) ========
__global__ __launch_bounds__(256, 4) void k_scan2(const ushort* __restrict__ deltab,
                                                  const ushort* __restrict__ xcb,
                                                  const ushort* __restrict__ xzb,
                                                  const float* __restrict__ BCbuf,
                                                  const float* __restrict__ anv,
                                                  const ushort* __restrict__ Hinit,
                                                  const float* __restrict__ Dw,
                                                  ushort* __restrict__ ygb){
  __shared__ ushort dl_s[16][260];
  __shared__ ushort xc_s[16][260];
  __shared__ ushort z_s [16][260];
  __shared__ float bcs[LCH][32];
  int bid = blockIdx.x;
  int b = bid >> 8;
  int g = (bid >> 1) & 127;
  int dh = bid & 1;
  int t = threadIdx.x;
  int d = dh * 256 + t;
  int base = b * SEQ + g * LCH;
  // ---- coalesced staging: 3 tiles x 512 int4-slots, 6 loads/thread ----
#pragma unroll
  for (int i = 0; i < 6; ++i) {
    int slot = i * 256 + t;            // [0,1536)
    int tile = slot >> 9;              // 0:delta 1:xc 2:z
    int idx = slot & 511;
    int row = idx >> 5, c16 = idx & 31;
    int col = dh * 256 + c16 * 8;
    size_t grow = (size_t)(base + row);
    int4 v;
    if (tile == 0)      v = *reinterpret_cast<const int4*>(&deltab[grow * 512 + col]);
    else if (tile == 1) v = *reinterpret_cast<const int4*>(&xcb[grow * 512 + col]);
    else                v = *reinterpret_cast<const int4*>(&xzb[grow * 1024 + 512 + col]);
    ushort (*dst)[260] = (tile == 0) ? dl_s : (tile == 1) ? xc_s : z_s;
    *reinterpret_cast<int4*>(&dst[row][c16 * 8]) = v;
  }
  {
    float2 v = *reinterpret_cast<const float2*>(&BCbuf[(size_t)base * 32 + t * 2]);
    *reinterpret_cast<float2*>(&((float*)bcs)[t * 2]) = v;
  }
  __syncthreads();
  float an[16], h[16];
  size_t hb0 = ((size_t)(b * GCH + g) * 16) * 512 + d;
#pragma unroll
  for (int n = 0; n < 16; ++n) { an[n] = anv[n * 512 + d]; h[n] = bf2f(Hinit[hb0 + (size_t)n * 512]); }
  float Dd = Dw[d];
  for (int s = 0; s < LCH; ++s) {
    float dl = bf2f(dl_s[s][t]);
    float xv = bf2f(xc_s[s][t]);
    float dx = dl * xv;
    float y = 0.f;
#pragma unroll
    for (int n = 0; n < 16; ++n) {
      float dA = __expf(dl * an[n]);
      h[n] = dA * h[n] + dx * bcs[s][n];
      y += h[n] * bcs[s][16 + n];
    }
    float zg = silu_f(bf2f(z_s[s][t]));
    ygb[(size_t)(base + s) * 512 + d] = f2bf((y + xv * Dd) * zg);
  }
}

// ======== kernel 5: GEMM3 64x64 tiles (256 blocks) out = residual + yg.Wout^T ========
__global__ __launch_bounds__(256) void k_gemm3(const ushort* __restrict__ A,
                                               const ushort* __restrict__ B,
                                               const float* __restrict__ x,
                                               float* __restrict__ out){
  __shared__ ushort Als[64][72];
  __shared__ ushort Bls[64][72];
  int m0 = blockIdx.x * 64, n0 = blockIdx.y * 64;
  int t = threadIdx.x;
  int w = t >> 6, l = t & 63;
  int wr = w >> 1, wc = w & 1;
  f32x4 acc[2][2] = {};
  int sr = t >> 3, sc = t & 7;
  for (int k0 = 0; k0 < DINNER; k0 += 64) {
#pragma unroll
    for (int p = 0; p < 2; ++p) {
      int r = sr + p * 32;
      *reinterpret_cast<int4*>(&Als[r][sc * 8]) =
        *reinterpret_cast<const int4*>(&A[((size_t)(m0 + r)) * DINNER + k0 + sc * 8]);
      *reinterpret_cast<int4*>(&Bls[r][sc * 8]) =
        *reinterpret_cast<const int4*>(&B[((size_t)(n0 + r)) * DINNER + k0 + sc * 8]);
    }
    __syncthreads();
#pragma unroll
    for (int ks = 0; ks < 2; ++ks) {
      s16x8 af[2], bf[2];
      int kk = ks * 32 + 8 * (l >> 4);
#pragma unroll
      for (int i = 0; i < 2; ++i) {
        af[i] = *reinterpret_cast<const s16x8*>(&Als[wr * 32 + i * 16 + (l & 15)][kk]);
        bf[i] = *reinterpret_cast<const s16x8*>(&Bls[wc * 32 + i * 16 + (l & 15)][kk]);
      }
#pragma unroll
      for (int mi = 0; mi < 2; ++mi)
#pragma unroll
        for (int ni = 0; ni < 2; ++ni)
          acc[mi][ni] = __builtin_amdgcn_mfma_f32_16x16x32_bf16(af[mi], bf[ni], acc[mi][ni], 0, 0, 0);
    }
    __syncthreads();
  }
  int rq = l >> 4, cc = l & 15;
#pragma unroll
  for (int mi = 0; mi < 2; ++mi)
#pragma unroll
    for (int ni = 0; ni < 2; ++ni) {
      int n = n0 + wc * 32 + ni * 16 + cc;
      int mB = m0 + wr * 32 + mi * 16 + rq * 4;
#pragma unroll
      for (int r2 = 0; r2 < 4; ++r2) {
        int m = mB + r2;
        int b = m >> 11;
        int lb = m & (SEQ - 1);
        size_t addr = ((size_t)(b * DMODEL + n)) * SEQ + lb;
        out[addr] = acc[mi][ni][r2] + x[addr];
      }
    }
}

extern "C" void kernel_launch(void* const* d_in, const int* in_sizes, int n_in,
                              void* d_out, int out_size, void* d_ws, size_t ws_size,
                              hipStream_t stream) {
  const float* x          = (const float*)d_in[0];
  const float* norm_w     = (const float*)d_in[1];
  const float* in_proj_w  = (const float*)d_in[2];
  const float* conv_w     = (const float*)d_in[3];
  const float* conv_b     = (const float*)d_in[4];
  const float* x_proj_w   = (const float*)d_in[5];
  const float* dt_proj_w  = (const float*)d_in[6];
  const float* dt_proj_b  = (const float*)d_in[7];
  const float* A_log      = (const float*)d_in[8];
  const float* Dw         = (const float*)d_in[9];
  const float* out_proj_w = (const float*)d_in[10];
  float* out = (float*)d_out;
  float* ws  = (float*)d_ws;

  float* BCbuf  = ws + OFF_BC;
  ushort* Sbuf  = (ushort*)(ws + OFF_S);
  ushort* Hinit = (ushort*)(ws + OFF_H);
  float* anv    = ws + OFF_ANV;
  float* sumd   = ws + OFF_SD;
  ushort* ub   = (ushort*)(ws + OFF_US);
  ushort* wob  = ub + UOFF_WOB;
  ushort* xzb  = ub + UOFF_XZ;
  ushort* xcb  = ub + UOFF_XC;
  ushort* delt = ub + UOFF_DL;
  ushort* ygb  = ub + UOFF_YG;
  ushort* xpwb = ub + UOFF_XPW;
  ushort* dtwb = ub + UOFF_DTW;

  k_g1   <<<256,          256, 0, stream>>>(x, norm_w, in_proj_w, out_proj_w, x_proj_w, dt_proj_w,
                                            A_log, wob, xpwb, dtwb, anv, xzb);
  k_xps1 <<<256,          512, 0, stream>>>(xzb, conv_w, conv_b, xpwb, dtwb, dt_proj_b, anv,
                                            xcb, BCbuf, delt, Sbuf, sumd);
  k_comb <<<1024,         256, 0, stream>>>(sumd, Sbuf, anv, Hinit);
  k_scan2<<<512,          256, 0, stream>>>(delt, xcb, xzb, BCbuf, anv, Hinit, Dw, ygb);
  k_gemm3<<<dim3(64, 4),  256, 0, stream>>>(ygb, wob, x, out);
}